// Round 1
// baseline (411.372 us; speedup 1.0000x reference)
//
#include <hip/hip_runtime.h>

#define Nn  2048
#define Aa  256
#define Cc  100
#define LAT 128
#define BN_EPS 1e-5f

// ws layout in floats
#define OFF_H    0                      // Nn*LAT
#define OFF_F    (Nn*LAT)               // Nn*Aa
#define OFF_SUMS (OFF_F + Nn*Aa)        // 256 (sum | sumsq)
#define OFF_SS   (OFF_SUMS + 256)       // 256 (scale | shift)
#define OFF_S    (OFF_SS + 256)         // Cc*Cc

// ---------------- K1: h = s @ W1^T + b1, plus per-col sum/sumsq ----------------
__global__ __launch_bounds__(256) void k1_gemm_h(
    const float* __restrict__ s, const float* __restrict__ W1,
    const float* __restrict__ b1, float* __restrict__ h, float* __restrict__ sums)
{
    __shared__ float sT[32][68];           // [k][row], BM=64
    __shared__ float wT[32][132];          // [k][col], BN=128
    __shared__ float red[2][16][128];
    const int t = threadIdx.x;
    const int row0 = blockIdx.x * 64;
    const int ri = t & 15, cj = t >> 4;
    const int rr = t >> 3;                 // 0..31
    const int kk4 = (t & 7) * 4;

    float acc[4][8];
#pragma unroll
    for (int m = 0; m < 4; m++)
#pragma unroll
        for (int n = 0; n < 8; n++) acc[m][n] = 0.f;

    for (int k0 = 0; k0 < Aa; k0 += 32) {
#pragma unroll
        for (int h2 = 0; h2 < 64; h2 += 32) {
            float4 v = *(const float4*)&s[(size_t)(row0 + rr + h2) * Aa + k0 + kk4];
            sT[kk4+0][rr+h2] = v.x; sT[kk4+1][rr+h2] = v.y;
            sT[kk4+2][rr+h2] = v.z; sT[kk4+3][rr+h2] = v.w;
        }
#pragma unroll
        for (int lh = 0; lh < 128; lh += 32) {
            float4 v = *(const float4*)&W1[(size_t)(rr + lh) * Aa + k0 + kk4];
            wT[kk4+0][rr+lh] = v.x; wT[kk4+1][rr+lh] = v.y;
            wT[kk4+2][rr+lh] = v.z; wT[kk4+3][rr+lh] = v.w;
        }
        __syncthreads();
#pragma unroll
        for (int kk = 0; kk < 32; kk++) {
            float4 av  = *(const float4*)&sT[kk][ri*4];
            float4 bv0 = *(const float4*)&wT[kk][cj*8];
            float4 bv1 = *(const float4*)&wT[kk][cj*8+4];
            float am[4] = {av.x, av.y, av.z, av.w};
            float bn[8] = {bv0.x,bv0.y,bv0.z,bv0.w,bv1.x,bv1.y,bv1.z,bv1.w};
#pragma unroll
            for (int m = 0; m < 4; m++)
#pragma unroll
                for (int n = 0; n < 8; n++)
                    acc[m][n] = fmaf(am[m], bn[n], acc[m][n]);
        }
        __syncthreads();
    }

    float s1[8], s2[8];
#pragma unroll
    for (int n = 0; n < 8; n++) { s1[n] = 0.f; s2[n] = 0.f; }
#pragma unroll
    for (int m = 0; m < 4; m++) {
        int row = row0 + ri*4 + m;
#pragma unroll
        for (int n = 0; n < 8; n++) {
            int col = cj*8 + n;
            float v = acc[m][n] + b1[col];
            h[(size_t)row * LAT + col] = v;
            s1[n] += v; s2[n] += v*v;
        }
    }
#pragma unroll
    for (int n = 0; n < 8; n++) {
        red[0][ri][cj*8+n] = s1[n];
        red[1][ri][cj*8+n] = s2[n];
    }
    __syncthreads();
    if (t < 128) {
        float a1 = 0.f, a2 = 0.f;
#pragma unroll
        for (int i2 = 0; i2 < 16; i2++) { a1 += red[0][i2][t]; a2 += red[1][i2][t]; }
        atomicAdd(&sums[t],       a1);
        atomicAdd(&sums[128 + t], a2);
    }
}

// ---------------- K2: finalize BN scale/shift ----------------
__global__ void k2_stats(const float* __restrict__ sums,
                         const float* __restrict__ gamma,
                         const float* __restrict__ beta,
                         float* __restrict__ ss)
{
    int l = threadIdx.x;
    if (l < LAT) {
        float mu  = sums[l] * (1.0f / Nn);
        float var = sums[LAT + l] * (1.0f / Nn) - mu * mu;
        float inv = rsqrtf(var + BN_EPS);
        float sc  = gamma[l] * inv;
        ss[l]       = sc;
        ss[LAT + l] = beta[l] - mu * sc;
    }
}

// ---------------- KS: S[k][c] = (Wfc[c]-Wfc[k]) cov[k] (Wfc[c]-Wfc[k])^T ------
// grid = 100 * 4 blocks; block (k, at) handles a in [at*64, at*64+64)
__global__ __launch_bounds__(256) void ks_kernel(
    const float* __restrict__ Wfc, const float* __restrict__ cov,
    float* __restrict__ S)
{
    __shared__ float Dt[32][260];          // c-tile of D, [c_local][b]
    const int t = threadIdx.x;
    const int k  = blockIdx.x >> 2;
    const int at = blockIdx.x & 3;
    const int A0 = at * 64;
    const int i = t & 15, j = t >> 4;
    const float* covk = cov + (size_t)k * (Aa * Aa);

    for (int ct = 0; ct < 4; ct++) {
        __syncthreads();                   // protect previous tile reads
        // stage Dt[cl][b] = Wfc[ct*32+cl][b] - Wfc[k][b]  (0 if col >= Cc)
        for (int idx = t * 4; idx < 32 * 256; idx += 1024) {
            int cl = idx >> 8, b = idx & 255;
            int cg = ct * 32 + cl;
            float4 wk = *(const float4*)&Wfc[(size_t)k * Aa + b];
            float4 v;
            if (cg < Cc) {
                float4 w = *(const float4*)&Wfc[(size_t)cg * Aa + b];
                v = make_float4(w.x - wk.x, w.y - wk.y, w.z - wk.z, w.w - wk.w);
            } else {
                v = make_float4(0.f, 0.f, 0.f, 0.f);
            }
            *(float4*)&Dt[cl][b] = v;
        }
        __syncthreads();

        float u[4][2] = {{0.f,0.f},{0.f,0.f},{0.f,0.f},{0.f,0.f}};
        for (int b0 = 0; b0 < Aa; b0 += 4) {
            float4 d0 = *(const float4*)&Dt[j][b0];
            float4 d1 = *(const float4*)&Dt[j + 16][b0];
#pragma unroll
            for (int m = 0; m < 4; m++) {
                int a = A0 + i + 16 * m;
                float4 cv = *(const float4*)&covk[(size_t)a * Aa + b0];
                u[m][0] = fmaf(cv.x, d0.x, fmaf(cv.y, d0.y,
                          fmaf(cv.z, d0.z, fmaf(cv.w, d0.w, u[m][0]))));
                u[m][1] = fmaf(cv.x, d1.x, fmaf(cv.y, d1.y,
                          fmaf(cv.z, d1.z, fmaf(cv.w, d1.w, u[m][1]))));
            }
        }
#pragma unroll
        for (int p = 0; p < 2; p++) {
            int cl = j + 16 * p;
            int c  = ct * 32 + cl;
            if (c < Cc) {
                float sp = 0.f;
#pragma unroll
                for (int m = 0; m < 4; m++)
                    sp = fmaf(Dt[cl][A0 + i + 16*m], u[m][p], sp);
                atomicAdd(&S[k * Cc + c], sp);
            }
        }
    }
}

// ---------------- K3: f = relu( relu(bn(h)) @ W2^T + b2 ) ----------------
__global__ __launch_bounds__(256) void k3_gemm_f(
    const float* __restrict__ h, const float* __restrict__ ss,
    const float* __restrict__ W2, const float* __restrict__ b2,
    float* __restrict__ f)
{
    __shared__ float hT[32][68];
    __shared__ float wT[32][68];
    const int t = threadIdx.x;
    const int row0 = (blockIdx.x & 31) * 64;
    const int col0 = (blockIdx.x >> 5) * 64;
    const int ri = t & 15, cj = t >> 4;
    const int rr = t >> 3;
    const int kk4 = (t & 7) * 4;

    float acc[4][4];
#pragma unroll
    for (int m = 0; m < 4; m++)
#pragma unroll
        for (int n = 0; n < 4; n++) acc[m][n] = 0.f;

    for (int k0 = 0; k0 < LAT; k0 += 32) {
        float sc0 = ss[k0+kk4+0], sc1 = ss[k0+kk4+1], sc2 = ss[k0+kk4+2], sc3 = ss[k0+kk4+3];
        float sh0 = ss[LAT+k0+kk4+0], sh1 = ss[LAT+k0+kk4+1], sh2 = ss[LAT+k0+kk4+2], sh3 = ss[LAT+k0+kk4+3];
#pragma unroll
        for (int h2 = 0; h2 < 64; h2 += 32) {
            float4 v = *(const float4*)&h[(size_t)(row0 + rr + h2) * LAT + k0 + kk4];
            hT[kk4+0][rr+h2] = fmaxf(fmaf(v.x, sc0, sh0), 0.f);
            hT[kk4+1][rr+h2] = fmaxf(fmaf(v.y, sc1, sh1), 0.f);
            hT[kk4+2][rr+h2] = fmaxf(fmaf(v.z, sc2, sh2), 0.f);
            hT[kk4+3][rr+h2] = fmaxf(fmaf(v.w, sc3, sh3), 0.f);
        }
#pragma unroll
        for (int ch = 0; ch < 64; ch += 32) {
            float4 v = *(const float4*)&W2[(size_t)(col0 + rr + ch) * LAT + k0 + kk4];
            wT[kk4+0][rr+ch] = v.x; wT[kk4+1][rr+ch] = v.y;
            wT[kk4+2][rr+ch] = v.z; wT[kk4+3][rr+ch] = v.w;
        }
        __syncthreads();
#pragma unroll
        for (int kk = 0; kk < 32; kk++) {
            float4 av = *(const float4*)&hT[kk][ri*4];
            float4 bv = *(const float4*)&wT[kk][cj*4];
            float am[4] = {av.x, av.y, av.z, av.w};
            float bn[4] = {bv.x, bv.y, bv.z, bv.w};
#pragma unroll
            for (int m = 0; m < 4; m++)
#pragma unroll
                for (int n = 0; n < 4; n++)
                    acc[m][n] = fmaf(am[m], bn[n], acc[m][n]);
        }
        __syncthreads();
    }
#pragma unroll
    for (int m = 0; m < 4; m++) {
        int row = row0 + ri*4 + m;
#pragma unroll
        for (int n = 0; n < 4; n++) {
            int col = col0 + cj*4 + n;
            f[(size_t)row * Aa + col] = fmaxf(acc[m][n] + b2[col], 0.f);
        }
    }
}

// ---------------- K4: out = f @ Wfc^T + bfc + coef * S[y[n]][c] ----------------
__global__ __launch_bounds__(256) void k4_gemm_out(
    const float* __restrict__ f, const float* __restrict__ Wfc,
    const float* __restrict__ bfc, const float* __restrict__ S,
    const int* __restrict__ y, const float* __restrict__ ratio,
    float* __restrict__ out)
{
    __shared__ float fT[32][68];
    __shared__ float wT[32][132];
    const int t = threadIdx.x;
    const int row0 = blockIdx.x * 64;
    const int ri = t & 15, cj = t >> 4;
    const int rr = t >> 3;
    const int kk4 = (t & 7) * 4;

    float acc[4][8];
#pragma unroll
    for (int m = 0; m < 4; m++)
#pragma unroll
        for (int n = 0; n < 8; n++) acc[m][n] = 0.f;

    for (int k0 = 0; k0 < Aa; k0 += 32) {
#pragma unroll
        for (int h2 = 0; h2 < 64; h2 += 32) {
            float4 v = *(const float4*)&f[(size_t)(row0 + rr + h2) * Aa + k0 + kk4];
            fT[kk4+0][rr+h2] = v.x; fT[kk4+1][rr+h2] = v.y;
            fT[kk4+2][rr+h2] = v.z; fT[kk4+3][rr+h2] = v.w;
        }
#pragma unroll
        for (int lh = 0; lh < 128; lh += 32) {
            int c = rr + lh;
            float4 v = make_float4(0.f, 0.f, 0.f, 0.f);
            if (c < Cc) v = *(const float4*)&Wfc[(size_t)c * Aa + k0 + kk4];
            wT[kk4+0][c] = v.x; wT[kk4+1][c] = v.y;
            wT[kk4+2][c] = v.z; wT[kk4+3][c] = v.w;
        }
        __syncthreads();
#pragma unroll
        for (int kk = 0; kk < 32; kk++) {
            float4 av  = *(const float4*)&fT[kk][ri*4];
            float4 bv0 = *(const float4*)&wT[kk][cj*8];
            float4 bv1 = *(const float4*)&wT[kk][cj*8+4];
            float am[4] = {av.x, av.y, av.z, av.w};
            float bn[8] = {bv0.x,bv0.y,bv0.z,bv0.w,bv1.x,bv1.y,bv1.z,bv1.w};
#pragma unroll
            for (int m = 0; m < 4; m++)
#pragma unroll
                for (int n = 0; n < 8; n++)
                    acc[m][n] = fmaf(am[m], bn[n], acc[m][n]);
        }
        __syncthreads();
    }

    float coef = 0.5f * ratio[0];
#pragma unroll
    for (int m = 0; m < 4; m++) {
        int row = row0 + ri*4 + m;
        int yv = y[row];
#pragma unroll
        for (int n = 0; n < 8; n++) {
            int col = cj*8 + n;
            if (col < Cc)
                out[(size_t)row * Cc + col] = acc[m][n] + bfc[col] + coef * S[yv * Cc + col];
        }
    }
}

extern "C" void kernel_launch(void* const* d_in, const int* in_sizes, int n_in,
                              void* d_out, int out_size, void* d_ws, size_t ws_size,
                              hipStream_t stream)
{
    const float* s     = (const float*)d_in[0];
    const int*   y     = (const int*)  d_in[1];
    const float* ratio = (const float*)d_in[2];
    const float* W1    = (const float*)d_in[3];
    const float* b1    = (const float*)d_in[4];
    const float* gamma = (const float*)d_in[5];
    const float* beta  = (const float*)d_in[6];
    const float* W2    = (const float*)d_in[7];
    const float* b2    = (const float*)d_in[8];
    const float* Wfc   = (const float*)d_in[9];
    const float* bfc   = (const float*)d_in[10];
    const float* cov   = (const float*)d_in[11];
    float* out = (float*)d_out;
    float* ws  = (float*)d_ws;

    // zero sums + scale/shift + S (atomically accumulated)
    hipMemsetAsync(ws + OFF_SUMS, 0, (size_t)(256 + 256 + Cc * Cc) * sizeof(float), stream);

    hipLaunchKernelGGL(k1_gemm_h,   dim3(32),  dim3(256), 0, stream,
                       s, W1, b1, ws + OFF_H, ws + OFF_SUMS);
    hipLaunchKernelGGL(k2_stats,    dim3(1),   dim3(128), 0, stream,
                       ws + OFF_SUMS, gamma, beta, ws + OFF_SS);
    hipLaunchKernelGGL(ks_kernel,   dim3(400), dim3(256), 0, stream,
                       Wfc, cov, ws + OFF_S);
    hipLaunchKernelGGL(k3_gemm_f,   dim3(128), dim3(256), 0, stream,
                       ws + OFF_H, ws + OFF_SS, W2, b2, ws + OFF_F);
    hipLaunchKernelGGL(k4_gemm_out, dim3(32),  dim3(256), 0, stream,
                       ws + OFF_F, Wfc, bfc, ws + OFF_S, y, ratio, out);
}

// Round 2
// 92.679 us; speedup vs baseline: 4.4387x; 4.4387x over previous
//
#include <hip/hip_runtime.h>

#define Nn  2048
#define Aa  256
#define Cc  100
#define LAT 128
#define BN_EPS 1e-5f

// ws layout in floats
#define OFF_H    0                      // Nn*LAT
#define OFF_F    (Nn*LAT)               // Nn*Aa
#define OFF_SUMS (OFF_F + Nn*Aa)        // 256 (sum | sumsq)
#define OFF_SS   (OFF_SUMS + 256)       // 256 (scale | shift)
#define OFF_S    (OFF_SS + 256)         // Cc*Cc

typedef __attribute__((ext_vector_type(8))) short bf16x8;
typedef __attribute__((ext_vector_type(4))) float f32x4;

__device__ __forceinline__ short f2bf(float f) {
    unsigned u = __float_as_uint(f);
    u = (u + 0x7FFFu + ((u >> 16) & 1u)) >> 16;
    return (short)u;
}
__device__ __forceinline__ float bf2f(short h) {
    return __uint_as_float(((unsigned)(unsigned short)h) << 16);
}

// ---------------- K1: h = s @ W1^T + b1, plus per-col sum/sumsq ----------------
__global__ __launch_bounds__(256) void k1_gemm_h(
    const float* __restrict__ s, const float* __restrict__ W1,
    const float* __restrict__ b1, float* __restrict__ h, float* __restrict__ sums)
{
    __shared__ float sT[32][68];           // [k][row], BM=64
    __shared__ float wT[32][132];          // [k][col], BN=128
    __shared__ float red[2][16][128];
    const int t = threadIdx.x;
    const int row0 = blockIdx.x * 64;
    const int ri = t & 15, cj = t >> 4;
    const int rr = t >> 3;                 // 0..31
    const int kk4 = (t & 7) * 4;

    float acc[4][8];
#pragma unroll
    for (int m = 0; m < 4; m++)
#pragma unroll
        for (int n = 0; n < 8; n++) acc[m][n] = 0.f;

    for (int k0 = 0; k0 < Aa; k0 += 32) {
#pragma unroll
        for (int h2 = 0; h2 < 64; h2 += 32) {
            float4 v = *(const float4*)&s[(size_t)(row0 + rr + h2) * Aa + k0 + kk4];
            sT[kk4+0][rr+h2] = v.x; sT[kk4+1][rr+h2] = v.y;
            sT[kk4+2][rr+h2] = v.z; sT[kk4+3][rr+h2] = v.w;
        }
#pragma unroll
        for (int lh = 0; lh < 128; lh += 32) {
            float4 v = *(const float4*)&W1[(size_t)(rr + lh) * Aa + k0 + kk4];
            wT[kk4+0][rr+lh] = v.x; wT[kk4+1][rr+lh] = v.y;
            wT[kk4+2][rr+lh] = v.z; wT[kk4+3][rr+lh] = v.w;
        }
        __syncthreads();
#pragma unroll
        for (int kk = 0; kk < 32; kk++) {
            float4 av  = *(const float4*)&sT[kk][ri*4];
            float4 bv0 = *(const float4*)&wT[kk][cj*8];
            float4 bv1 = *(const float4*)&wT[kk][cj*8+4];
            float am[4] = {av.x, av.y, av.z, av.w};
            float bn[8] = {bv0.x,bv0.y,bv0.z,bv0.w,bv1.x,bv1.y,bv1.z,bv1.w};
#pragma unroll
            for (int m = 0; m < 4; m++)
#pragma unroll
                for (int n = 0; n < 8; n++)
                    acc[m][n] = fmaf(am[m], bn[n], acc[m][n]);
        }
        __syncthreads();
    }

    float s1[8], s2[8];
#pragma unroll
    for (int n = 0; n < 8; n++) { s1[n] = 0.f; s2[n] = 0.f; }
#pragma unroll
    for (int m = 0; m < 4; m++) {
        int row = row0 + ri*4 + m;
#pragma unroll
        for (int n = 0; n < 8; n++) {
            int col = cj*8 + n;
            float v = acc[m][n] + b1[col];
            h[(size_t)row * LAT + col] = v;
            s1[n] += v; s2[n] += v*v;
        }
    }
#pragma unroll
    for (int n = 0; n < 8; n++) {
        red[0][ri][cj*8+n] = s1[n];
        red[1][ri][cj*8+n] = s2[n];
    }
    __syncthreads();
    if (t < 128) {
        float a1 = 0.f, a2 = 0.f;
#pragma unroll
        for (int i2 = 0; i2 < 16; i2++) { a1 += red[0][i2][t]; a2 += red[1][i2][t]; }
        atomicAdd(&sums[t],       a1);
        atomicAdd(&sums[128 + t], a2);
    }
}

// ---------------- K2: finalize BN scale/shift ----------------
__global__ void k2_stats(const float* __restrict__ sums,
                         const float* __restrict__ gamma,
                         const float* __restrict__ beta,
                         float* __restrict__ ss)
{
    int l = threadIdx.x;
    if (l < LAT) {
        float mu  = sums[l] * (1.0f / Nn);
        float var = sums[LAT + l] * (1.0f / Nn) - mu * mu;
        float inv = rsqrtf(var + BN_EPS);
        float sc  = gamma[l] * inv;
        ss[l]       = sc;
        ss[LAT + l] = beta[l] - mu * sc;
    }
}

// ---------------- KS (MFMA): S[k][c] = D cov[k] D^T diag, D = Wfc - Wfc[k] ----
// P[c,b] = sum_a D[c,a] cov[k][a,b];  S[k,c] = sum_b P[c,b] D[c,b]
// grid = 100*2 blocks: block (k, nh) owns b in [nh*128, nh*128+128), 4 waves
// of 32 b-cols each. A-operand (D) staged bf16 in LDS; B-operand read from
// global using cov symmetry: B[a][b] = cov[b][a] = contiguous row read.
#define KSM 7          // M-frags: 112 c-rows (100 real + 12 zero)
#define DPITCH 264     // bf16 pitch: 528 B, 16B-multiple, odd*16 -> conflict-free b128

__global__ __launch_bounds__(256) void ks_mfma(
    const float* __restrict__ Wfc, const float* __restrict__ cov,
    float* __restrict__ S)
{
    __shared__ short Dlds[112 * DPITCH];   // 59,136 B
    const int t  = threadIdx.x;
    const int k  = blockIdx.x >> 1;
    const int nh = blockIdx.x & 1;
    const float* covk = cov + (size_t)k * (Aa * Aa);

    // ---- stage D rows 0..111 (rows >= 100 zero), fully coalesced ----
    {
        const int c4 = t & 63;                       // float4 slot in row
        float4 wk = *(const float4*)&Wfc[(size_t)k * Aa + c4 * 4];
#pragma unroll
        for (int j = 0; j < 28; j++) {
            int row = (t >> 6) + j * 4;
            short4 o;
            if (row < Cc) {
                float4 v = *(const float4*)&Wfc[(size_t)row * Aa + c4 * 4];
                o.x = f2bf(v.x - wk.x); o.y = f2bf(v.y - wk.y);
                o.z = f2bf(v.z - wk.z); o.w = f2bf(v.w - wk.w);
            } else {
                o.x = 0; o.y = 0; o.z = 0; o.w = 0;
            }
            *(short4*)&Dlds[row * DPITCH + c4 * 4] = o;
        }
    }
    __syncthreads();

    const int w  = t >> 6;          // wave 0..3
    const int l  = t & 63;
    const int il = l & 15;
    const int q  = l >> 4;
    const int bbase = nh * 128 + w * 32;

    f32x4 acc[KSM][2];
#pragma unroll
    for (int m = 0; m < KSM; m++) {
        acc[m][0] = (f32x4){0.f, 0.f, 0.f, 0.f};
        acc[m][1] = (f32x4){0.f, 0.f, 0.f, 0.f};
    }

    const float* brow0 = covk + (size_t)(bbase + il) * Aa;
    const float* brow1 = covk + (size_t)(bbase + 16 + il) * Aa;

#pragma unroll
    for (int sgk = 0; sgk < 8; sgk++) {
        const int a0 = sgk * 32 + q * 8;
        bf16x8 bm0, bm1;
        {
            float4 u0 = *(const float4*)&brow0[a0];
            float4 u1 = *(const float4*)&brow0[a0 + 4];
            bm0[0] = f2bf(u0.x); bm0[1] = f2bf(u0.y); bm0[2] = f2bf(u0.z); bm0[3] = f2bf(u0.w);
            bm0[4] = f2bf(u1.x); bm0[5] = f2bf(u1.y); bm0[6] = f2bf(u1.z); bm0[7] = f2bf(u1.w);
            float4 v0 = *(const float4*)&brow1[a0];
            float4 v1 = *(const float4*)&brow1[a0 + 4];
            bm1[0] = f2bf(v0.x); bm1[1] = f2bf(v0.y); bm1[2] = f2bf(v0.z); bm1[3] = f2bf(v0.w);
            bm1[4] = f2bf(v1.x); bm1[5] = f2bf(v1.y); bm1[6] = f2bf(v1.z); bm1[7] = f2bf(v1.w);
        }
#pragma unroll
        for (int m = 0; m < KSM; m++) {
            bf16x8 am = *(bf16x8*)&Dlds[(m * 16 + il) * DPITCH + a0];
            acc[m][0] = __builtin_amdgcn_mfma_f32_16x16x32_bf16(am, bm0, acc[m][0], 0, 0, 0);
            acc[m][1] = __builtin_amdgcn_mfma_f32_16x16x32_bf16(am, bm1, acc[m][1], 0, 0, 0);
        }
    }

    // ---- epilogue: S[k,c] += sum_b P[c,b] * D[c,b] ----
#pragma unroll
    for (int m = 0; m < KSM; m++) {
        float sacc[4] = {0.f, 0.f, 0.f, 0.f};
#pragma unroll
        for (int nf = 0; nf < 2; nf++) {
            int bcol = bbase + nf * 16 + il;
#pragma unroll
            for (int r = 0; r < 4; r++) {
                int crow = m * 16 + q * 4 + r;
                float dv = bf2f(Dlds[crow * DPITCH + bcol]);
                sacc[r] = fmaf(dv, acc[m][nf][r], sacc[r]);
            }
        }
#pragma unroll
        for (int r = 0; r < 4; r++) {
            float v = sacc[r];
            v += __shfl_xor(v, 1);
            v += __shfl_xor(v, 2);
            v += __shfl_xor(v, 4);
            v += __shfl_xor(v, 8);
            int crow = m * 16 + q * 4 + r;
            if (il == 0 && crow < Cc)
                atomicAdd(&S[k * Cc + crow], v);
        }
    }
}

// ---------------- K3: f = relu( relu(bn(h)) @ W2^T + b2 ) ----------------
__global__ __launch_bounds__(256) void k3_gemm_f(
    const float* __restrict__ h, const float* __restrict__ ss,
    const float* __restrict__ W2, const float* __restrict__ b2,
    float* __restrict__ f)
{
    __shared__ float hT[32][68];
    __shared__ float wT[32][68];
    const int t = threadIdx.x;
    const int row0 = (blockIdx.x & 31) * 64;
    const int col0 = (blockIdx.x >> 5) * 64;
    const int ri = t & 15, cj = t >> 4;
    const int rr = t >> 3;
    const int kk4 = (t & 7) * 4;

    float acc[4][4];
#pragma unroll
    for (int m = 0; m < 4; m++)
#pragma unroll
        for (int n = 0; n < 4; n++) acc[m][n] = 0.f;

    for (int k0 = 0; k0 < LAT; k0 += 32) {
        float sc0 = ss[k0+kk4+0], sc1 = ss[k0+kk4+1], sc2 = ss[k0+kk4+2], sc3 = ss[k0+kk4+3];
        float sh0 = ss[LAT+k0+kk4+0], sh1 = ss[LAT+k0+kk4+1], sh2 = ss[LAT+k0+kk4+2], sh3 = ss[LAT+k0+kk4+3];
#pragma unroll
        for (int h2 = 0; h2 < 64; h2 += 32) {
            float4 v = *(const float4*)&h[(size_t)(row0 + rr + h2) * LAT + k0 + kk4];
            hT[kk4+0][rr+h2] = fmaxf(fmaf(v.x, sc0, sh0), 0.f);
            hT[kk4+1][rr+h2] = fmaxf(fmaf(v.y, sc1, sh1), 0.f);
            hT[kk4+2][rr+h2] = fmaxf(fmaf(v.z, sc2, sh2), 0.f);
            hT[kk4+3][rr+h2] = fmaxf(fmaf(v.w, sc3, sh3), 0.f);
        }
#pragma unroll
        for (int ch = 0; ch < 64; ch += 32) {
            float4 v = *(const float4*)&W2[(size_t)(col0 + rr + ch) * LAT + k0 + kk4];
            wT[kk4+0][rr+ch] = v.x; wT[kk4+1][rr+ch] = v.y;
            wT[kk4+2][rr+ch] = v.z; wT[kk4+3][rr+ch] = v.w;
        }
        __syncthreads();
#pragma unroll
        for (int kk = 0; kk < 32; kk++) {
            float4 av = *(const float4*)&hT[kk][ri*4];
            float4 bv = *(const float4*)&wT[kk][cj*4];
            float am[4] = {av.x, av.y, av.z, av.w};
            float bn[4] = {bv.x, bv.y, bv.z, bv.w};
#pragma unroll
            for (int m = 0; m < 4; m++)
#pragma unroll
                for (int n = 0; n < 4; n++)
                    acc[m][n] = fmaf(am[m], bn[n], acc[m][n]);
        }
        __syncthreads();
    }
#pragma unroll
    for (int m = 0; m < 4; m++) {
        int row = row0 + ri*4 + m;
#pragma unroll
        for (int n = 0; n < 4; n++) {
            int col = col0 + cj*4 + n;
            f[(size_t)row * Aa + col] = fmaxf(acc[m][n] + b2[col], 0.f);
        }
    }
}

// ---------------- K4: out = f @ Wfc^T + bfc + coef * S[y[n]][c] ----------------
__global__ __launch_bounds__(256) void k4_gemm_out(
    const float* __restrict__ f, const float* __restrict__ Wfc,
    const float* __restrict__ bfc, const float* __restrict__ S,
    const int* __restrict__ y, const float* __restrict__ ratio,
    float* __restrict__ out)
{
    __shared__ float fT[32][68];
    __shared__ float wT[32][132];
    const int t = threadIdx.x;
    const int row0 = blockIdx.x * 64;
    const int ri = t & 15, cj = t >> 4;
    const int rr = t >> 3;
    const int kk4 = (t & 7) * 4;

    float acc[4][8];
#pragma unroll
    for (int m = 0; m < 4; m++)
#pragma unroll
        for (int n = 0; n < 8; n++) acc[m][n] = 0.f;

    for (int k0 = 0; k0 < Aa; k0 += 32) {
#pragma unroll
        for (int h2 = 0; h2 < 64; h2 += 32) {
            float4 v = *(const float4*)&f[(size_t)(row0 + rr + h2) * Aa + k0 + kk4];
            fT[kk4+0][rr+h2] = v.x; fT[kk4+1][rr+h2] = v.y;
            fT[kk4+2][rr+h2] = v.z; fT[kk4+3][rr+h2] = v.w;
        }
#pragma unroll
        for (int lh = 0; lh < 128; lh += 32) {
            int c = rr + lh;
            float4 v = make_float4(0.f, 0.f, 0.f, 0.f);
            if (c < Cc) v = *(const float4*)&Wfc[(size_t)c * Aa + k0 + kk4];
            wT[kk4+0][c] = v.x; wT[kk4+1][c] = v.y;
            wT[kk4+2][c] = v.z; wT[kk4+3][c] = v.w;
        }
        __syncthreads();
#pragma unroll
        for (int kk = 0; kk < 32; kk++) {
            float4 av  = *(const float4*)&fT[kk][ri*4];
            float4 bv0 = *(const float4*)&wT[kk][cj*8];
            float4 bv1 = *(const float4*)&wT[kk][cj*8+4];
            float am[4] = {av.x, av.y, av.z, av.w};
            float bn[8] = {bv0.x,bv0.y,bv0.z,bv0.w,bv1.x,bv1.y,bv1.z,bv1.w};
#pragma unroll
            for (int m = 0; m < 4; m++)
#pragma unroll
                for (int n = 0; n < 8; n++)
                    acc[m][n] = fmaf(am[m], bn[n], acc[m][n]);
        }
        __syncthreads();
    }

    float coef = 0.5f * ratio[0];
#pragma unroll
    for (int m = 0; m < 4; m++) {
        int row = row0 + ri*4 + m;
        int yv = y[row];
#pragma unroll
        for (int n = 0; n < 8; n++) {
            int col = cj*8 + n;
            if (col < Cc)
                out[(size_t)row * Cc + col] = acc[m][n] + bfc[col] + coef * S[yv * Cc + col];
        }
    }
}

extern "C" void kernel_launch(void* const* d_in, const int* in_sizes, int n_in,
                              void* d_out, int out_size, void* d_ws, size_t ws_size,
                              hipStream_t stream)
{
    const float* s     = (const float*)d_in[0];
    const int*   y     = (const int*)  d_in[1];
    const float* ratio = (const float*)d_in[2];
    const float* W1    = (const float*)d_in[3];
    const float* b1    = (const float*)d_in[4];
    const float* gamma = (const float*)d_in[5];
    const float* beta  = (const float*)d_in[6];
    const float* W2    = (const float*)d_in[7];
    const float* b2    = (const float*)d_in[8];
    const float* Wfc   = (const float*)d_in[9];
    const float* bfc   = (const float*)d_in[10];
    const float* cov   = (const float*)d_in[11];
    float* out = (float*)d_out;
    float* ws  = (float*)d_ws;

    // zero sums + scale/shift + S (atomically accumulated)
    hipMemsetAsync(ws + OFF_SUMS, 0, (size_t)(256 + 256 + Cc * Cc) * sizeof(float), stream);

    hipLaunchKernelGGL(k1_gemm_h,   dim3(32),  dim3(256), 0, stream,
                       s, W1, b1, ws + OFF_H, ws + OFF_SUMS);
    hipLaunchKernelGGL(k2_stats,    dim3(1),   dim3(128), 0, stream,
                       ws + OFF_SUMS, gamma, beta, ws + OFF_SS);
    hipLaunchKernelGGL(ks_mfma,     dim3(200), dim3(256), 0, stream,
                       Wfc, cov, ws + OFF_S);
    hipLaunchKernelGGL(k3_gemm_f,   dim3(128), dim3(256), 0, stream,
                       ws + OFF_H, ws + OFF_SS, W2, b2, ws + OFF_F);
    hipLaunchKernelGGL(k4_gemm_out, dim3(32),  dim3(256), 0, stream,
                       ws + OFF_F, Wfc, bfc, ws + OFF_S, y, ratio, out);
}

// Round 3
// 90.314 us; speedup vs baseline: 4.5549x; 1.0262x over previous
//
#include <hip/hip_runtime.h>

#define Nn  2048
#define Aa  256
#define Cc  100
#define LAT 128
#define BN_EPS 1e-5f

// ws layout in floats (everything fully overwritten each call -> no zeroing)
#define OFF_H    0                        // Nn*LAT
#define OFF_F    (Nn*LAT)                 // Nn*Aa
#define OFF_SUMS (OFF_F + Nn*Aa)          // 32 blocks * 256 (sum[128] | sumsq[128])
#define OFF_S    (OFF_SUMS + 32*256)      // Cc*Cc

typedef __attribute__((ext_vector_type(8))) short bf16x8;
typedef __attribute__((ext_vector_type(4))) float f32x4;

__device__ __forceinline__ short f2bf(float f) {
    unsigned u = __float_as_uint(f);
    u = (u + 0x7FFFu + ((u >> 16) & 1u)) >> 16;
    return (short)u;
}
__device__ __forceinline__ float bf2f(short h) {
    return __uint_as_float(((unsigned)(unsigned short)h) << 16);
}

// ---------------- K1: h = s @ W1^T + b1, plus per-block col sum/sumsq ---------
__global__ __launch_bounds__(256) void k1_gemm_h(
    const float* __restrict__ s, const float* __restrict__ W1,
    const float* __restrict__ b1, float* __restrict__ h, float* __restrict__ sums)
{
    __shared__ float sT[32][68];           // [k][row], BM=64
    __shared__ float wT[32][132];          // [k][col], BN=128
    __shared__ float red[2][16][128];
    const int t = threadIdx.x;
    const int row0 = blockIdx.x * 64;
    const int ri = t & 15, cj = t >> 4;
    const int rr = t >> 3;                 // 0..31
    const int kk4 = (t & 7) * 4;

    float acc[4][8];
#pragma unroll
    for (int m = 0; m < 4; m++)
#pragma unroll
        for (int n = 0; n < 8; n++) acc[m][n] = 0.f;

    for (int k0 = 0; k0 < Aa; k0 += 32) {
#pragma unroll
        for (int h2 = 0; h2 < 64; h2 += 32) {
            float4 v = *(const float4*)&s[(size_t)(row0 + rr + h2) * Aa + k0 + kk4];
            sT[kk4+0][rr+h2] = v.x; sT[kk4+1][rr+h2] = v.y;
            sT[kk4+2][rr+h2] = v.z; sT[kk4+3][rr+h2] = v.w;
        }
#pragma unroll
        for (int lh = 0; lh < 128; lh += 32) {
            float4 v = *(const float4*)&W1[(size_t)(rr + lh) * Aa + k0 + kk4];
            wT[kk4+0][rr+lh] = v.x; wT[kk4+1][rr+lh] = v.y;
            wT[kk4+2][rr+lh] = v.z; wT[kk4+3][rr+lh] = v.w;
        }
        __syncthreads();
#pragma unroll
        for (int kk = 0; kk < 32; kk++) {
            float4 av  = *(const float4*)&sT[kk][ri*4];
            float4 bv0 = *(const float4*)&wT[kk][cj*8];
            float4 bv1 = *(const float4*)&wT[kk][cj*8+4];
            float am[4] = {av.x, av.y, av.z, av.w};
            float bn[8] = {bv0.x,bv0.y,bv0.z,bv0.w,bv1.x,bv1.y,bv1.z,bv1.w};
#pragma unroll
            for (int m = 0; m < 4; m++)
#pragma unroll
                for (int n = 0; n < 8; n++)
                    acc[m][n] = fmaf(am[m], bn[n], acc[m][n]);
        }
        __syncthreads();
    }

    float s1[8], s2[8];
#pragma unroll
    for (int n = 0; n < 8; n++) { s1[n] = 0.f; s2[n] = 0.f; }
#pragma unroll
    for (int m = 0; m < 4; m++) {
        int row = row0 + ri*4 + m;
#pragma unroll
        for (int n = 0; n < 8; n++) {
            int col = cj*8 + n;
            float v = acc[m][n] + b1[col];
            h[(size_t)row * LAT + col] = v;
            s1[n] += v; s2[n] += v*v;
        }
    }
#pragma unroll
    for (int n = 0; n < 8; n++) {
        red[0][ri][cj*8+n] = s1[n];
        red[1][ri][cj*8+n] = s2[n];
    }
    __syncthreads();
    if (t < 128) {
        float a1 = 0.f, a2 = 0.f;
#pragma unroll
        for (int i2 = 0; i2 < 16; i2++) { a1 += red[0][i2][t]; a2 += red[1][i2][t]; }
        sums[blockIdx.x * 256 + t]       = a1;    // per-block partial, no atomic
        sums[blockIdx.x * 256 + 128 + t] = a2;
    }
}

// ---------------- KS (MFMA): S[k][c] = diag(D cov[k] D^T), D = Wfc - Wfc[k] ---
// grid = 100 blocks: block k owns the full b-range 256; 4 waves of 64 b-cols.
// A-operand (D) staged bf16 in LDS; B-operand via cov symmetry: contiguous rows.
#define KSM 7          // M-frags: 112 c-rows (100 real + 12 zero)
#define DPITCH 264     // bf16 pitch: 528 B, odd multiple of 16B

__global__ __launch_bounds__(256) void ks_mfma(
    const float* __restrict__ Wfc, const float* __restrict__ cov,
    float* __restrict__ S)
{
    __shared__ short Dlds[112 * DPITCH];   // 59,136 B
    __shared__ float red[4][112];          // +1,792 B
    const int t = threadIdx.x;
    const int k = blockIdx.x;
    const float* covk = cov + (size_t)k * (Aa * Aa);

    // ---- stage D rows 0..111 (rows >= 100 zero), coalesced ----
    {
        const int c4 = t & 63;                       // float4 slot in row
        float4 wk = *(const float4*)&Wfc[(size_t)k * Aa + c4 * 4];
#pragma unroll
        for (int j = 0; j < 28; j++) {
            int row = (t >> 6) + j * 4;
            short4 o;
            if (row < Cc) {
                float4 v = *(const float4*)&Wfc[(size_t)row * Aa + c4 * 4];
                o.x = f2bf(v.x - wk.x); o.y = f2bf(v.y - wk.y);
                o.z = f2bf(v.z - wk.z); o.w = f2bf(v.w - wk.w);
            } else {
                o.x = 0; o.y = 0; o.z = 0; o.w = 0;
            }
            *(short4*)&Dlds[row * DPITCH + c4 * 4] = o;
        }
    }
    __syncthreads();

    const int w  = t >> 6;          // wave 0..3
    const int l  = t & 63;
    const int il = l & 15;
    const int q  = l >> 4;
    const int bbase = w * 64;

    f32x4 acc[KSM][4];
#pragma unroll
    for (int m = 0; m < KSM; m++)
#pragma unroll
        for (int nf = 0; nf < 4; nf++)
            acc[m][nf] = (f32x4){0.f, 0.f, 0.f, 0.f};

    const float* brow0 = covk + (size_t)(bbase +  0 + il) * Aa;
    const float* brow1 = covk + (size_t)(bbase + 16 + il) * Aa;
    const float* brow2 = covk + (size_t)(bbase + 32 + il) * Aa;
    const float* brow3 = covk + (size_t)(bbase + 48 + il) * Aa;

#pragma unroll
    for (int sgk = 0; sgk < 8; sgk++) {
        const int a0 = sgk * 32 + q * 8;
        bf16x8 bm[4];
        {
            const float* br[4] = {brow0, brow1, brow2, brow3};
#pragma unroll
            for (int nf = 0; nf < 4; nf++) {
                float4 u0 = *(const float4*)&br[nf][a0];
                float4 u1 = *(const float4*)&br[nf][a0 + 4];
                bm[nf][0] = f2bf(u0.x); bm[nf][1] = f2bf(u0.y);
                bm[nf][2] = f2bf(u0.z); bm[nf][3] = f2bf(u0.w);
                bm[nf][4] = f2bf(u1.x); bm[nf][5] = f2bf(u1.y);
                bm[nf][6] = f2bf(u1.z); bm[nf][7] = f2bf(u1.w);
            }
        }
#pragma unroll
        for (int m = 0; m < KSM; m++) {
            bf16x8 am = *(bf16x8*)&Dlds[(m * 16 + il) * DPITCH + a0];
#pragma unroll
            for (int nf = 0; nf < 4; nf++)
                acc[m][nf] = __builtin_amdgcn_mfma_f32_16x16x32_bf16(am, bm[nf], acc[m][nf], 0, 0, 0);
        }
    }

    // ---- epilogue: per-wave partial S, reduce across waves in LDS ----
#pragma unroll
    for (int m = 0; m < KSM; m++) {
        float sacc[4] = {0.f, 0.f, 0.f, 0.f};
#pragma unroll
        for (int nf = 0; nf < 4; nf++) {
            int bcol = bbase + nf * 16 + il;
#pragma unroll
            for (int r = 0; r < 4; r++) {
                int crow = m * 16 + q * 4 + r;
                float dv = bf2f(Dlds[crow * DPITCH + bcol]);
                sacc[r] = fmaf(dv, acc[m][nf][r], sacc[r]);
            }
        }
#pragma unroll
        for (int r = 0; r < 4; r++) {
            float v = sacc[r];
            v += __shfl_xor(v, 1);
            v += __shfl_xor(v, 2);
            v += __shfl_xor(v, 4);
            v += __shfl_xor(v, 8);
            if (il == 0) red[w][m * 16 + q * 4 + r] = v;
        }
    }
    __syncthreads();
    if (t < Cc)
        S[k * Cc + t] = red[0][t] + red[1][t] + red[2][t] + red[3][t];
}

// ---------------- K3: f = relu( relu(bn(h)) @ W2^T + b2 ), stats inlined ------
__global__ __launch_bounds__(256) void k3_gemm_f(
    const float* __restrict__ h, const float* __restrict__ sums,
    const float* __restrict__ gamma, const float* __restrict__ beta,
    const float* __restrict__ W2, const float* __restrict__ b2,
    float* __restrict__ f)
{
    __shared__ float hT[32][68];
    __shared__ float wT[32][68];
    __shared__ float scL[128], shL[128];
    const int t = threadIdx.x;
    const int row0 = (blockIdx.x & 31) * 64;
    const int col0 = (blockIdx.x >> 5) * 64;
    const int ri = t & 15, cj = t >> 4;
    const int rr = t >> 3;
    const int kk4 = (t & 7) * 4;

    if (t < 128) {
        float a1 = 0.f, a2 = 0.f;
#pragma unroll
        for (int b = 0; b < 32; b++) {
            a1 += sums[b * 256 + t];
            a2 += sums[b * 256 + 128 + t];
        }
        float mu  = a1 * (1.0f / Nn);
        float var = a2 * (1.0f / Nn) - mu * mu;
        float inv = rsqrtf(var + BN_EPS);
        float sc  = gamma[t] * inv;
        scL[t] = sc;
        shL[t] = beta[t] - mu * sc;
    }
    __syncthreads();

    float acc[4][4];
#pragma unroll
    for (int m = 0; m < 4; m++)
#pragma unroll
        for (int n = 0; n < 4; n++) acc[m][n] = 0.f;

    for (int k0 = 0; k0 < LAT; k0 += 32) {
        float sc0 = scL[k0+kk4+0], sc1 = scL[k0+kk4+1], sc2 = scL[k0+kk4+2], sc3 = scL[k0+kk4+3];
        float sh0 = shL[k0+kk4+0], sh1 = shL[k0+kk4+1], sh2 = shL[k0+kk4+2], sh3 = shL[k0+kk4+3];
#pragma unroll
        for (int h2 = 0; h2 < 64; h2 += 32) {
            float4 v = *(const float4*)&h[(size_t)(row0 + rr + h2) * LAT + k0 + kk4];
            hT[kk4+0][rr+h2] = fmaxf(fmaf(v.x, sc0, sh0), 0.f);
            hT[kk4+1][rr+h2] = fmaxf(fmaf(v.y, sc1, sh1), 0.f);
            hT[kk4+2][rr+h2] = fmaxf(fmaf(v.z, sc2, sh2), 0.f);
            hT[kk4+3][rr+h2] = fmaxf(fmaf(v.w, sc3, sh3), 0.f);
        }
#pragma unroll
        for (int ch = 0; ch < 64; ch += 32) {
            float4 v = *(const float4*)&W2[(size_t)(col0 + rr + ch) * LAT + k0 + kk4];
            wT[kk4+0][rr+ch] = v.x; wT[kk4+1][rr+ch] = v.y;
            wT[kk4+2][rr+ch] = v.z; wT[kk4+3][rr+ch] = v.w;
        }
        __syncthreads();
#pragma unroll
        for (int kk = 0; kk < 32; kk++) {
            float4 av = *(const float4*)&hT[kk][ri*4];
            float4 bv = *(const float4*)&wT[kk][cj*4];
            float am[4] = {av.x, av.y, av.z, av.w};
            float bn[4] = {bv.x, bv.y, bv.z, bv.w};
#pragma unroll
            for (int m = 0; m < 4; m++)
#pragma unroll
                for (int n = 0; n < 4; n++)
                    acc[m][n] = fmaf(am[m], bn[n], acc[m][n]);
        }
        __syncthreads();
    }
#pragma unroll
    for (int m = 0; m < 4; m++) {
        int row = row0 + ri*4 + m;
#pragma unroll
        for (int n = 0; n < 4; n++) {
            int col = col0 + cj*4 + n;
            f[(size_t)row * Aa + col] = fmaxf(acc[m][n] + b2[col], 0.f);
        }
    }
}

// ---------------- K4: out = f @ Wfc^T + bfc + coef * S[y[n]][c] ----------------
__global__ __launch_bounds__(256) void k4_gemm_out(
    const float* __restrict__ f, const float* __restrict__ Wfc,
    const float* __restrict__ bfc, const float* __restrict__ S,
    const int* __restrict__ y, const float* __restrict__ ratio,
    float* __restrict__ out)
{
    __shared__ float fT[32][68];
    __shared__ float wT[32][132];
    const int t = threadIdx.x;
    const int row0 = blockIdx.x * 64;
    const int ri = t & 15, cj = t >> 4;
    const int rr = t >> 3;
    const int kk4 = (t & 7) * 4;

    float acc[4][8];
#pragma unroll
    for (int m = 0; m < 4; m++)
#pragma unroll
        for (int n = 0; n < 8; n++) acc[m][n] = 0.f;

    for (int k0 = 0; k0 < Aa; k0 += 32) {
#pragma unroll
        for (int h2 = 0; h2 < 64; h2 += 32) {
            float4 v = *(const float4*)&f[(size_t)(row0 + rr + h2) * Aa + k0 + kk4];
            fT[kk4+0][rr+h2] = v.x; fT[kk4+1][rr+h2] = v.y;
            fT[kk4+2][rr+h2] = v.z; fT[kk4+3][rr+h2] = v.w;
        }
#pragma unroll
        for (int lh = 0; lh < 128; lh += 32) {
            int c = rr + lh;
            float4 v = make_float4(0.f, 0.f, 0.f, 0.f);
            if (c < Cc) v = *(const float4*)&Wfc[(size_t)c * Aa + k0 + kk4];
            wT[kk4+0][c] = v.x; wT[kk4+1][c] = v.y;
            wT[kk4+2][c] = v.z; wT[kk4+3][c] = v.w;
        }
        __syncthreads();
#pragma unroll
        for (int kk = 0; kk < 32; kk++) {
            float4 av  = *(const float4*)&fT[kk][ri*4];
            float4 bv0 = *(const float4*)&wT[kk][cj*8];
            float4 bv1 = *(const float4*)&wT[kk][cj*8+4];
            float am[4] = {av.x, av.y, av.z, av.w};
            float bn[8] = {bv0.x,bv0.y,bv0.z,bv0.w,bv1.x,bv1.y,bv1.z,bv1.w};
#pragma unroll
            for (int m = 0; m < 4; m++)
#pragma unroll
                for (int n = 0; n < 8; n++)
                    acc[m][n] = fmaf(am[m], bn[n], acc[m][n]);
        }
        __syncthreads();
    }

    float coef = 0.5f * ratio[0];
#pragma unroll
    for (int m = 0; m < 4; m++) {
        int row = row0 + ri*4 + m;
        int yv = y[row];
#pragma unroll
        for (int n = 0; n < 8; n++) {
            int col = cj*8 + n;
            if (col < Cc)
                out[(size_t)row * Cc + col] = acc[m][n] + bfc[col] + coef * S[yv * Cc + col];
        }
    }
}

extern "C" void kernel_launch(void* const* d_in, const int* in_sizes, int n_in,
                              void* d_out, int out_size, void* d_ws, size_t ws_size,
                              hipStream_t stream)
{
    const float* s     = (const float*)d_in[0];
    const int*   y     = (const int*)  d_in[1];
    const float* ratio = (const float*)d_in[2];
    const float* W1    = (const float*)d_in[3];
    const float* b1    = (const float*)d_in[4];
    const float* gamma = (const float*)d_in[5];
    const float* beta  = (const float*)d_in[6];
    const float* W2    = (const float*)d_in[7];
    const float* b2    = (const float*)d_in[8];
    const float* Wfc   = (const float*)d_in[9];
    const float* bfc   = (const float*)d_in[10];
    const float* cov   = (const float*)d_in[11];
    float* out = (float*)d_out;
    float* ws  = (float*)d_ws;

    hipLaunchKernelGGL(k1_gemm_h,   dim3(32),  dim3(256), 0, stream,
                       s, W1, b1, ws + OFF_H, ws + OFF_SUMS);
    hipLaunchKernelGGL(ks_mfma,     dim3(100), dim3(256), 0, stream,
                       Wfc, cov, ws + OFF_S);
    hipLaunchKernelGGL(k3_gemm_f,   dim3(128), dim3(256), 0, stream,
                       ws + OFF_H, ws + OFF_SUMS, gamma, beta, W2, b2, ws + OFF_F);
    hipLaunchKernelGGL(k4_gemm_out, dim3(32),  dim3(256), 0, stream,
                       ws + OFF_F, Wfc, bfc, ws + OFF_S, y, ratio, out);
}

// Round 4
// 49.376 us; speedup vs baseline: 8.3315x; 1.8291x over previous
//
#include <hip/hip_runtime.h>

#define Nn  2048
#define Aa  256
#define Cc  100
#define LAT 128
#define BN_EPS 1e-5f

// ws layout in floats (everything fully overwritten each call -> no zeroing)
#define OFF_HB   0                           // h bf16 [2048][128] -> 131072 floats
#define OFF_FB   (OFF_HB + Nn*LAT/2)         // f bf16 [2048][256] -> 262144 floats
#define OFF_SUMS (OFF_FB + Nn*Aa/2)          // 128 blocks * 256 f32
#define OFF_S    (OFF_SUMS + 128*256)        // Cc*Cc f32
#define OFF_W1B  (OFF_S + Cc*Cc)             // W1 bf16 [128][256] -> 16384 floats
#define OFF_W2B  (OFF_W1B + LAT*Aa/2)        // W2 bf16 [256][128] -> 16384 floats
#define OFF_WFB  (OFF_W2B + Aa*LAT/2)        // Wfc bf16 padded [128][256] -> 16384 floats

typedef __attribute__((ext_vector_type(8))) short bf16x8;
typedef __attribute__((ext_vector_type(4))) float f32x4;

__device__ __forceinline__ short f2bf(float f) {
    unsigned u = __float_as_uint(f);
    u = (u + 0x7FFFu + ((u >> 16) & 1u)) >> 16;
    return (short)u;
}
__device__ __forceinline__ float bf2f(short h) {
    return __uint_as_float(((unsigned)(unsigned short)h) << 16);
}

// ---------------- KPREP: weights -> bf16 (Wfc zero-padded to 128 rows) --------
__global__ __launch_bounds__(256) void kprep(
    const float* __restrict__ W1, const float* __restrict__ W2,
    const float* __restrict__ Wfc,
    short* __restrict__ W1b, short* __restrict__ W2b, short* __restrict__ Wfcb)
{
    const int b = blockIdx.x, t = threadIdx.x;
    const int e = (b & 31) * 1024 + t * 4;
    if (b < 32) {
        float4 v = *(const float4*)&W1[e];
        short4 o = {f2bf(v.x), f2bf(v.y), f2bf(v.z), f2bf(v.w)};
        *(short4*)&W1b[e] = o;
    } else if (b < 64) {
        float4 v = *(const float4*)&W2[e];
        short4 o = {f2bf(v.x), f2bf(v.y), f2bf(v.z), f2bf(v.w)};
        *(short4*)&W2b[e] = o;
    } else {
        int row = e >> 8;
        short4 o = {0, 0, 0, 0};
        if (row < Cc) {
            float4 v = *(const float4*)&Wfc[e];
            o.x = f2bf(v.x); o.y = f2bf(v.y); o.z = f2bf(v.z); o.w = f2bf(v.w);
        }
        *(short4*)&Wfcb[e] = o;
    }
}

// ---------------- K1 (MFMA): h = s @ W1^T + b1 (bf16 out) + per-block stats ---
// grid 128: block owns 16 rows x full N=128; 4 waves, wave w cols [w*32,w*32+32)
__global__ __launch_bounds__(256) void k1_mfma(
    const float* __restrict__ s, const short* __restrict__ W1b,
    const float* __restrict__ b1, short* __restrict__ hB, float* __restrict__ sums)
{
    const int t = threadIdx.x;
    const int w = t >> 6, l = t & 63, il = l & 15, q = l >> 4;
    const int row0 = blockIdx.x * 16;
    const int colw = w * 32;

    f32x4 acc[2];
    acc[0] = (f32x4){0.f,0.f,0.f,0.f};
    acc[1] = (f32x4){0.f,0.f,0.f,0.f};

    const float* arow = s + (size_t)(row0 + il) * Aa;
    const short* bp0 = W1b + (size_t)(colw + il) * Aa;
    const short* bp1 = W1b + (size_t)(colw + 16 + il) * Aa;

#pragma unroll
    for (int ks = 0; ks < 8; ks++) {
        const int k0 = ks * 32 + q * 8;
        float4 u0 = *(const float4*)&arow[k0];
        float4 u1 = *(const float4*)&arow[k0 + 4];
        bf16x8 am;
        am[0]=f2bf(u0.x); am[1]=f2bf(u0.y); am[2]=f2bf(u0.z); am[3]=f2bf(u0.w);
        am[4]=f2bf(u1.x); am[5]=f2bf(u1.y); am[6]=f2bf(u1.z); am[7]=f2bf(u1.w);
        bf16x8 bm0 = *(const bf16x8*)&bp0[k0];
        bf16x8 bm1 = *(const bf16x8*)&bp1[k0];
        acc[0] = __builtin_amdgcn_mfma_f32_16x16x32_bf16(am, bm0, acc[0], 0, 0, 0);
        acc[1] = __builtin_amdgcn_mfma_f32_16x16x32_bf16(am, bm1, acc[1], 0, 0, 0);
    }

#pragma unroll
    for (int n = 0; n < 2; n++) {
        const int col = colw + n * 16 + il;
        const float bias = b1[col];
        float s1 = 0.f, s2 = 0.f;
#pragma unroll
        for (int r = 0; r < 4; r++) {
            float v = acc[n][r] + bias;
            hB[(size_t)(row0 + q * 4 + r) * LAT + col] = f2bf(v);
            s1 += v; s2 += v * v;
        }
        s1 += __shfl_xor(s1, 16); s1 += __shfl_xor(s1, 32);
        s2 += __shfl_xor(s2, 16); s2 += __shfl_xor(s2, 32);
        if (q == 0) {
            sums[blockIdx.x * 256 + col]       = s1;
            sums[blockIdx.x * 256 + 128 + col] = s2;
        }
    }
}

// ---------------- KS (MFMA): S[k][c] = diag(D cov[k] D^T), D = Wfc - Wfc[k] ---
#define KSM 7
#define DPITCH 264

__global__ __launch_bounds__(256) void ks_mfma(
    const float* __restrict__ Wfc, const float* __restrict__ cov,
    float* __restrict__ S)
{
    __shared__ short Dlds[112 * DPITCH];
    __shared__ float red[4][112];
    const int t = threadIdx.x;
    const int k = blockIdx.x;
    const float* covk = cov + (size_t)k * (Aa * Aa);

    {
        const int c4 = t & 63;
        float4 wk = *(const float4*)&Wfc[(size_t)k * Aa + c4 * 4];
#pragma unroll
        for (int j = 0; j < 28; j++) {
            int row = (t >> 6) + j * 4;
            short4 o;
            if (row < Cc) {
                float4 v = *(const float4*)&Wfc[(size_t)row * Aa + c4 * 4];
                o.x = f2bf(v.x - wk.x); o.y = f2bf(v.y - wk.y);
                o.z = f2bf(v.z - wk.z); o.w = f2bf(v.w - wk.w);
            } else {
                o.x = 0; o.y = 0; o.z = 0; o.w = 0;
            }
            *(short4*)&Dlds[row * DPITCH + c4 * 4] = o;
        }
    }
    __syncthreads();

    const int w  = t >> 6;
    const int l  = t & 63;
    const int il = l & 15;
    const int q  = l >> 4;
    const int bbase = w * 64;

    f32x4 acc[KSM][4];
#pragma unroll
    for (int m = 0; m < KSM; m++)
#pragma unroll
        for (int nf = 0; nf < 4; nf++)
            acc[m][nf] = (f32x4){0.f, 0.f, 0.f, 0.f};

    const float* brow0 = covk + (size_t)(bbase +  0 + il) * Aa;
    const float* brow1 = covk + (size_t)(bbase + 16 + il) * Aa;
    const float* brow2 = covk + (size_t)(bbase + 32 + il) * Aa;
    const float* brow3 = covk + (size_t)(bbase + 48 + il) * Aa;

#pragma unroll
    for (int sgk = 0; sgk < 8; sgk++) {
        const int a0 = sgk * 32 + q * 8;
        bf16x8 bm[4];
        {
            const float* br[4] = {brow0, brow1, brow2, brow3};
#pragma unroll
            for (int nf = 0; nf < 4; nf++) {
                float4 u0 = *(const float4*)&br[nf][a0];
                float4 u1 = *(const float4*)&br[nf][a0 + 4];
                bm[nf][0] = f2bf(u0.x); bm[nf][1] = f2bf(u0.y);
                bm[nf][2] = f2bf(u0.z); bm[nf][3] = f2bf(u0.w);
                bm[nf][4] = f2bf(u1.x); bm[nf][5] = f2bf(u1.y);
                bm[nf][6] = f2bf(u1.z); bm[nf][7] = f2bf(u1.w);
            }
        }
#pragma unroll
        for (int m = 0; m < KSM; m++) {
            bf16x8 am = *(bf16x8*)&Dlds[(m * 16 + il) * DPITCH + a0];
#pragma unroll
            for (int nf = 0; nf < 4; nf++)
                acc[m][nf] = __builtin_amdgcn_mfma_f32_16x16x32_bf16(am, bm[nf], acc[m][nf], 0, 0, 0);
        }
    }

#pragma unroll
    for (int m = 0; m < KSM; m++) {
        float sacc[4] = {0.f, 0.f, 0.f, 0.f};
#pragma unroll
        for (int nf = 0; nf < 4; nf++) {
            int bcol = bbase + nf * 16 + il;
#pragma unroll
            for (int r = 0; r < 4; r++) {
                int crow = m * 16 + q * 4 + r;
                float dv = bf2f(Dlds[crow * DPITCH + bcol]);
                sacc[r] = fmaf(dv, acc[m][nf][r], sacc[r]);
            }
        }
#pragma unroll
        for (int r = 0; r < 4; r++) {
            float v = sacc[r];
            v += __shfl_xor(v, 1);
            v += __shfl_xor(v, 2);
            v += __shfl_xor(v, 4);
            v += __shfl_xor(v, 8);
            if (il == 0) red[w][m * 16 + q * 4 + r] = v;
        }
    }
    __syncthreads();
    if (t < Cc)
        S[k * Cc + t] = red[0][t] + red[1][t] + red[2][t] + red[3][t];
}

// ---------------- K3 (MFMA): f = relu(relu(bn(h)) @ W2^T + b2), bf16 out ------
// grid 128: block owns 16 rows x full N=256; 4 waves, wave w cols [w*64,w*64+64)
__global__ __launch_bounds__(256) void k3_mfma(
    const short* __restrict__ hB, const float* __restrict__ sums,
    const float* __restrict__ gamma, const float* __restrict__ beta,
    const short* __restrict__ W2b, const float* __restrict__ b2,
    short* __restrict__ fB)
{
    __shared__ float scL[LAT], shL[LAT];
    const int t = threadIdx.x;
    if (t < 128) {
        float a1 = 0.f, a2 = 0.f;
#pragma unroll 8
        for (int b = 0; b < 128; b++) {
            a1 += sums[b * 256 + t];
            a2 += sums[b * 256 + 128 + t];
        }
        float mu  = a1 * (1.0f / Nn);
        float var = a2 * (1.0f / Nn) - mu * mu;
        float inv = rsqrtf(var + BN_EPS);
        float sc  = gamma[t] * inv;
        scL[t] = sc;
        shL[t] = beta[t] - mu * sc;
    }
    __syncthreads();

    const int w = t >> 6, l = t & 63, il = l & 15, q = l >> 4;
    const int row0 = blockIdx.x * 16;
    const int colw = w * 64;

    f32x4 acc[4];
#pragma unroll
    for (int n = 0; n < 4; n++) acc[n] = (f32x4){0.f,0.f,0.f,0.f};

    const short* arow = hB + (size_t)(row0 + il) * LAT;

#pragma unroll
    for (int ks = 0; ks < 4; ks++) {
        const int k0 = ks * 32 + q * 8;
        bf16x8 ha = *(const bf16x8*)&arow[k0];
        bf16x8 am;
#pragma unroll
        for (int j = 0; j < 8; j++) {
            float fv = fmaf(bf2f(ha[j]), scL[k0 + j], shL[k0 + j]);
            am[j] = f2bf(fmaxf(fv, 0.f));
        }
#pragma unroll
        for (int n = 0; n < 4; n++) {
            bf16x8 bm = *(const bf16x8*)&W2b[(size_t)(colw + n * 16 + il) * LAT + k0];
            acc[n] = __builtin_amdgcn_mfma_f32_16x16x32_bf16(am, bm, acc[n], 0, 0, 0);
        }
    }

#pragma unroll
    for (int n = 0; n < 4; n++) {
        const int col = colw + n * 16 + il;
        const float bias = b2[col];
#pragma unroll
        for (int r = 0; r < 4; r++) {
            float v = fmaxf(acc[n][r] + bias, 0.f);
            fB[(size_t)(row0 + q * 4 + r) * Aa + col] = f2bf(v);
        }
    }
}

// ---------------- K4 (MFMA): out = f @ Wfc^T + bfc + coef * S[y[n]][c] --------
// grid 128: block owns 16 rows x padded N=128; 4 waves, wave w cols [w*32,...)
__global__ __launch_bounds__(256) void k4_mfma(
    const short* __restrict__ fB, const short* __restrict__ Wfcb,
    const float* __restrict__ bfc, const float* __restrict__ S,
    const int* __restrict__ y, const float* __restrict__ ratio,
    float* __restrict__ out)
{
    const int t = threadIdx.x;
    const int w = t >> 6, l = t & 63, il = l & 15, q = l >> 4;
    const int row0 = blockIdx.x * 16;
    const int colw = w * 32;

    f32x4 acc[2];
    acc[0] = (f32x4){0.f,0.f,0.f,0.f};
    acc[1] = (f32x4){0.f,0.f,0.f,0.f};

    const short* arow = fB + (size_t)(row0 + il) * Aa;
    const short* bp0 = Wfcb + (size_t)(colw + il) * Aa;
    const short* bp1 = Wfcb + (size_t)(colw + 16 + il) * Aa;

#pragma unroll
    for (int ks = 0; ks < 8; ks++) {
        const int k0 = ks * 32 + q * 8;
        bf16x8 am  = *(const bf16x8*)&arow[k0];
        bf16x8 bm0 = *(const bf16x8*)&bp0[k0];
        bf16x8 bm1 = *(const bf16x8*)&bp1[k0];
        acc[0] = __builtin_amdgcn_mfma_f32_16x16x32_bf16(am, bm0, acc[0], 0, 0, 0);
        acc[1] = __builtin_amdgcn_mfma_f32_16x16x32_bf16(am, bm1, acc[1], 0, 0, 0);
    }

    const float coef = 0.5f * ratio[0];
    const int4 yv4 = *(const int4*)&y[row0 + q * 4];
    const int yr[4] = {yv4.x, yv4.y, yv4.z, yv4.w};

#pragma unroll
    for (int n = 0; n < 2; n++) {
        const int col = colw + n * 16 + il;
        if (col < Cc) {
            const float bias = bfc[col];
#pragma unroll
            for (int r = 0; r < 4; r++) {
                out[(size_t)(row0 + q * 4 + r) * Cc + col] =
                    acc[n][r] + bias + coef * S[yr[r] * Cc + col];
            }
        }
    }
}

extern "C" void kernel_launch(void* const* d_in, const int* in_sizes, int n_in,
                              void* d_out, int out_size, void* d_ws, size_t ws_size,
                              hipStream_t stream)
{
    const float* s     = (const float*)d_in[0];
    const int*   y     = (const int*)  d_in[1];
    const float* ratio = (const float*)d_in[2];
    const float* W1    = (const float*)d_in[3];
    const float* b1    = (const float*)d_in[4];
    const float* gamma = (const float*)d_in[5];
    const float* beta  = (const float*)d_in[6];
    const float* W2    = (const float*)d_in[7];
    const float* b2    = (const float*)d_in[8];
    const float* Wfc   = (const float*)d_in[9];
    const float* bfc   = (const float*)d_in[10];
    const float* cov   = (const float*)d_in[11];
    float* out = (float*)d_out;
    float* ws  = (float*)d_ws;

    short* hB   = (short*)(ws + OFF_HB);
    short* fB   = (short*)(ws + OFF_FB);
    short* W1b  = (short*)(ws + OFF_W1B);
    short* W2b  = (short*)(ws + OFF_W2B);
    short* Wfcb = (short*)(ws + OFF_WFB);

    hipLaunchKernelGGL(kprep,   dim3(96),  dim3(256), 0, stream,
                       W1, W2, Wfc, W1b, W2b, Wfcb);
    hipLaunchKernelGGL(k1_mfma, dim3(128), dim3(256), 0, stream,
                       s, W1b, b1, hB, ws + OFF_SUMS);
    hipLaunchKernelGGL(ks_mfma, dim3(100), dim3(256), 0, stream,
                       Wfc, cov, ws + OFF_S);
    hipLaunchKernelGGL(k3_mfma, dim3(128), dim3(256), 0, stream,
                       hB, ws + OFF_SUMS, gamma, beta, W2b, b2, fB);
    hipLaunchKernelGGL(k4_mfma, dim3(128), dim3(256), 0, stream,
                       fB, Wfcb, bfc, ws + OFF_S, y, ratio, out);
}